// Round 1
// baseline (41.068 us; speedup 1.0000x reference)
//
#include <hip/hip_runtime.h>

typedef _Float16 f16;
typedef _Float16 f16x8 __attribute__((ext_vector_type(8)));
typedef float    f32x4 __attribute__((ext_vector_type(4)));

#define NB 32
#define ND 256
#define NT 1024

// ---------------------------------------------------------------------------
// Kernel A: depthwise causal conv via dual-exponential IIR scan.
// One wave per (b,n) row; lane l owns t in [16l, 16l+16).
// k[u] = om*(d^u - m^u), S_a[t] = x[t] + a*S_a[t-1]  =>  y = om*(S_d - S_m).
// ---------------------------------------------------------------------------
__global__ __launch_bounds__(256) void iir_scan_kernel(
    const float* __restrict__ x, const float* __restrict__ tau_rise,
    const float* __restrict__ tau_decay, const float* __restrict__ omega,
    f16* __restrict__ y16)
{
    const int lane = threadIdx.x & 63;
    const int wid  = threadIdx.x >> 6;
    const int row  = blockIdx.x * 4 + wid;      // b*ND + n
    const int n    = row & (ND - 1);

    const float td = tau_decay[n];
    const float tr = tau_rise[n];
    const float om = omega[n];
    const float ad = expf(-1.0f / td);
    const float am = expf(-(1.0f / tr + 1.0f / td));

    const float* xr = x + (size_t)row * NT + lane * 16;
    float xv[16];
    #pragma unroll
    for (int i = 0; i < 4; ++i) {
        f32x4 v = *reinterpret_cast<const f32x4*>(xr + i * 4);
        xv[i*4+0] = v[0]; xv[i*4+1] = v[1]; xv[i*4+2] = v[2]; xv[i*4+3] = v[3];
    }

    // local (carry-free) inclusive scans, both states
    float ld[16], lm[16];
    float sd = 0.f, sm = 0.f;
    #pragma unroll
    for (int i = 0; i < 16; ++i) {
        sd = fmaf(ad, sd, xv[i]); ld[i] = sd;
        sm = fmaf(am, sm, xv[i]); lm[i] = sm;
    }

    // a^16 for each state
    float t2;
    t2 = ad * ad; t2 = t2 * t2; t2 = t2 * t2; const float a16d = t2 * t2;
    t2 = am * am; t2 = t2 * t2; t2 = t2 * t2; const float a16m = t2 * t2;

    // weighted Kogge-Stone across lanes: X_l = sum_j a16^(l-j) H_j
    float Xd = sd, Xm = sm;
    float wdp = a16d, wmp = a16m;
    #pragma unroll
    for (int off = 1; off < 64; off <<= 1) {
        float pd = __shfl_up(Xd, off);
        float pm = __shfl_up(Xm, off);
        if (lane >= off) { Xd = fmaf(wdp, pd, Xd); Xm = fmaf(wmp, pm, Xm); }
        wdp *= wdp; wmp *= wmp;
    }
    // exclusive carry = running state at end of previous lane's chunk
    float cd = __shfl_up(Xd, 1);
    float cm = __shfl_up(Xm, 1);
    if (lane == 0) { cd = 0.f; cm = 0.f; }

    // reconstruct: S[16l+i] = local_i + a^(i+1) * carry
    f16x8 o0, o1;
    float pd = ad, pm = am;
    #pragma unroll
    for (int i = 0; i < 16; ++i) {
        float yd = fmaf(pd, cd, ld[i]);
        float ym = fmaf(pm, cm, lm[i]);
        float yv = om * (yd - ym);
        if (i < 8) o0[i] = (f16)yv; else o1[i - 8] = (f16)yv;
        pd *= ad; pm *= am;
    }
    f16* dst = y16 + (size_t)row * NT + lane * 16;
    *reinterpret_cast<f16x8*>(dst)     = o0;
    *reinterpret_cast<f16x8*>(dst + 8) = o1;
}

// ---------------------------------------------------------------------------
// Kernel C: pack Wm = W (diag zeroed) into fp16 MFMA A-fragment order.
// Layout: [nh(2)][ks(8)][nt(8)][lane(64)][j(8)],
//   value = Wm[n = nh*128 + nt*16 + (lane&15)][m = ks*32 + (lane>>4)*8 + j]
// ---------------------------------------------------------------------------
__global__ __launch_bounds__(256) void wprep_kernel(
    const float* __restrict__ W, f16* __restrict__ wf)
{
    const int gid  = blockIdx.x * 256 + threadIdx.x;   // 0..8191
    const int nh   = gid >> 12;
    const int rem  = gid & 4095;
    const int ks   = rem >> 9;
    const int nt   = (rem >> 6) & 7;
    const int lane = rem & 63;
    const int nrow = nh * 128 + nt * 16 + (lane & 15);
    const int m0   = ks * 32 + (lane >> 4) * 8;
    f16x8 v;
    #pragma unroll
    for (int j = 0; j < 8; ++j) {
        int m = m0 + j;
        float w = W[nrow * 256 + m];
        v[j] = (f16)((m == nrow) ? 0.0f : w);
    }
    *reinterpret_cast<f16x8*>(wf + (size_t)gid * 8) = v;
}

// ---------------------------------------------------------------------------
// Kernel B: out[b,t] = sum_n y[n,t]*(z[n,t]+1) - 70,  z = Wm*y  (per b).
// Block = (b, t-tile of 64, n-half of 128). 4 waves, wave w owns t's w*16..+16.
// W-frags staged linearly in LDS (64KB); Y tile staged transposed [t][m] with
// XOR swizzle (u16 idx ^= (t&7)<<3) for conflict-free ds_read_b128 B-frags.
// ---------------------------------------------------------------------------
__global__ __launch_bounds__(256, 1) void bilinear_kernel(
    const f16* __restrict__ y16, const f16* __restrict__ wf,
    float* __restrict__ out)
{
    __shared__ __align__(16) f16 Wl[32768];   // 64 KB
    __shared__ __align__(16) f16 Yl[16384];   // 32 KB

    const int bi = blockIdx.x;
    const int nh = bi & 1;
    const int tt = (bi >> 1) & 15;
    const int b  = bi >> 5;
    const int t0 = tt * 64;
    const int tid = threadIdx.x;

    // stage this half's W fragments: 64KB contiguous
    const f16* wsrc = wf + (size_t)nh * 32768;
    #pragma unroll
    for (int k = 0; k < 16; ++k) {
        int chunk = k * 256 + tid;
        *reinterpret_cast<f16x8*>(&Wl[chunk * 8]) =
            *reinterpret_cast<const f16x8*>(&wsrc[(size_t)chunk * 8]);
    }

    // stage Y tile: thread tid = m, streams its row's 128B window, transposes
    {
        const int m = tid;
        const f16* ysrc = y16 + ((size_t)(b * ND + m)) * NT + t0;
        #pragma unroll
        for (int c = 0; c < 8; ++c) {
            f16x8 v = *reinterpret_cast<const f16x8*>(ysrc + c * 8);
            #pragma unroll
            for (int e = 0; e < 8; ++e) {
                int tl = c * 8 + e;                 // tl&7 == e
                Yl[tl * 256 + (m ^ (e << 3))] = v[e];
            }
        }
    }
    __syncthreads();

    const int lane = tid & 63;
    const int w    = tid >> 6;
    const int tl   = w * 16 + (lane & 15);   // this lane's t column
    const int g    = lane >> 4;
    const int sw   = (tl & 7) << 3;

    f32x4 acc[8];
    #pragma unroll
    for (int i = 0; i < 8; ++i) acc[i] = (f32x4){0.f, 0.f, 0.f, 0.f};

    #pragma unroll
    for (int ks = 0; ks < 8; ++ks) {
        const int k0 = ks * 32 + g * 8;
        f16x8 bfrag = *reinterpret_cast<const f16x8*>(&Yl[tl * 256 + (k0 ^ sw)]);
        #pragma unroll
        for (int nt = 0; nt < 8; ++nt) {
            f16x8 afrag = *reinterpret_cast<const f16x8*>(
                &Wl[((ks * 8 + nt) * 64 + lane) * 8]);
            acc[nt] = __builtin_amdgcn_mfma_f32_16x16x32_f16(
                afrag, bfrag, acc[nt], 0, 0, 0);
        }
    }

    // epilogue: partial = sum over this lane's C rows of y*(z+1)
    float part = 0.f;
    #pragma unroll
    for (int nt = 0; nt < 8; ++nt) {
        #pragma unroll
        for (int r = 0; r < 4; ++r) {
            int ng = nh * 128 + nt * 16 + g * 4 + r;   // global n of this C elem
            float yv = (float)Yl[tl * 256 + (ng ^ sw)];
            part = fmaf(yv, acc[nt][r] + 1.0f, part);
        }
    }
    // reduce the 4 lanes sharing the same t (l, l^16, l^32, l^48)
    part += __shfl_xor(part, 16);
    part += __shfl_xor(part, 32);
    if (lane < 16) {
        float add = part + (nh == 0 ? -70.0f : 0.0f);
        atomicAdd(&out[b * NT + t0 + w * 16 + lane], add);
    }
}

// ---------------------------------------------------------------------------
extern "C" void kernel_launch(void* const* d_in, const int* in_sizes, int n_in,
                              void* d_out, int out_size, void* d_ws, size_t ws_size,
                              hipStream_t stream) {
    const float* x         = (const float*)d_in[0];
    const float* tau_rise  = (const float*)d_in[1];
    const float* tau_decay = (const float*)d_in[2];
    const float* omega     = (const float*)d_in[3];
    const float* W         = (const float*)d_in[4];
    float* out = (float*)d_out;

    f16* y16 = (f16*)d_ws;                                        // 16 MB
    f16* wfr = (f16*)((char*)d_ws + (size_t)16 * 1024 * 1024);    // 128 KB

    hipMemsetAsync(d_out, 0, (size_t)out_size * sizeof(float), stream);
    wprep_kernel<<<32, 256, 0, stream>>>(W, wfr);
    iir_scan_kernel<<<(NB * ND) / 4, 256, 0, stream>>>(x, tau_rise, tau_decay, omega, y16);
    bilinear_kernel<<<NB * 16 * 2, 256, 0, stream>>>(y16, wfr, out);
}

// Round 2
// 28.728 us; speedup vs baseline: 1.4295x; 1.4295x over previous
//
#include <hip/hip_runtime.h>

typedef _Float16 f16;
typedef _Float16 f16x8 __attribute__((ext_vector_type(8)));
typedef float    f32x4 __attribute__((ext_vector_type(4)));

#define NB 32
#define ND 256
#define NT 1024

// ---------------------------------------------------------------------------
// Kernel A: depthwise causal conv via dual-exponential IIR scan.
// One wave per (b,n) row; lane l owns t in [16l, 16l+16).
// k[u] = om*(d^u - m^u), S_a[t] = x[t] + a*S_a[t-1]  =>  y = om*(S_d - S_m).
// ---------------------------------------------------------------------------
__global__ __launch_bounds__(256) void iir_scan_kernel(
    const float* __restrict__ x, const float* __restrict__ tau_rise,
    const float* __restrict__ tau_decay, const float* __restrict__ omega,
    f16* __restrict__ y16)
{
    const int lane = threadIdx.x & 63;
    const int wid  = threadIdx.x >> 6;
    const int row  = blockIdx.x * 4 + wid;      // b*ND + n
    const int n    = row & (ND - 1);

    const float td = tau_decay[n];
    const float tr = tau_rise[n];
    const float om = omega[n];
    const float ad = expf(-1.0f / td);
    const float am = expf(-(1.0f / tr + 1.0f / td));

    const float* xr = x + (size_t)row * NT + lane * 16;
    float xv[16];
    #pragma unroll
    for (int i = 0; i < 4; ++i) {
        f32x4 v = *reinterpret_cast<const f32x4*>(xr + i * 4);
        xv[i*4+0] = v[0]; xv[i*4+1] = v[1]; xv[i*4+2] = v[2]; xv[i*4+3] = v[3];
    }

    // local (carry-free) inclusive scans, both states
    float ld[16], lm[16];
    float sd = 0.f, sm = 0.f;
    #pragma unroll
    for (int i = 0; i < 16; ++i) {
        sd = fmaf(ad, sd, xv[i]); ld[i] = sd;
        sm = fmaf(am, sm, xv[i]); lm[i] = sm;
    }

    // a^16 for each state
    float t2;
    t2 = ad * ad; t2 = t2 * t2; t2 = t2 * t2; const float a16d = t2 * t2;
    t2 = am * am; t2 = t2 * t2; t2 = t2 * t2; const float a16m = t2 * t2;

    // weighted Kogge-Stone across lanes: X_l = sum_j a16^(l-j) H_j
    float Xd = sd, Xm = sm;
    float wdp = a16d, wmp = a16m;
    #pragma unroll
    for (int off = 1; off < 64; off <<= 1) {
        float pd = __shfl_up(Xd, off);
        float pm = __shfl_up(Xm, off);
        if (lane >= off) { Xd = fmaf(wdp, pd, Xd); Xm = fmaf(wmp, pm, Xm); }
        wdp *= wdp; wmp *= wmp;
    }
    // exclusive carry = running state at end of previous lane's chunk
    float cd = __shfl_up(Xd, 1);
    float cm = __shfl_up(Xm, 1);
    if (lane == 0) { cd = 0.f; cm = 0.f; }

    // reconstruct: S[16l+i] = local_i + a^(i+1) * carry
    f16x8 o0, o1;
    float pd = ad, pm = am;
    #pragma unroll
    for (int i = 0; i < 16; ++i) {
        float yd = fmaf(pd, cd, ld[i]);
        float ym = fmaf(pm, cm, lm[i]);
        float yv = om * (yd - ym);
        if (i < 8) o0[i] = (f16)yv; else o1[i - 8] = (f16)yv;
        pd *= ad; pm *= am;
    }
    f16* dst = y16 + (size_t)row * NT + lane * 16;
    *reinterpret_cast<f16x8*>(dst)     = o0;
    *reinterpret_cast<f16x8*>(dst + 8) = o1;
}

// ---------------------------------------------------------------------------
// Kernel C: pack Wm = W (diag zeroed) into fp16 MFMA A-fragment order.
// Layout: [nh(2)][ks(8)][nt(8)][lane(64)][j(8)],
//   value = Wm[n = nh*128 + nt*16 + (lane&15)][m = ks*32 + (lane>>4)*8 + j]
// ---------------------------------------------------------------------------
__global__ __launch_bounds__(256) void wprep_kernel(
    const float* __restrict__ W, f16* __restrict__ wf)
{
    const int gid  = blockIdx.x * 256 + threadIdx.x;   // 0..8191
    const int nh   = gid >> 12;
    const int rem  = gid & 4095;
    const int ks   = rem >> 9;
    const int nt   = (rem >> 6) & 7;
    const int lane = rem & 63;
    const int nrow = nh * 128 + nt * 16 + (lane & 15);
    const int m0   = ks * 32 + (lane >> 4) * 8;
    f16x8 v;
    #pragma unroll
    for (int j = 0; j < 8; ++j) {
        int m = m0 + j;
        float w = W[nrow * 256 + m];
        v[j] = (f16)((m == nrow) ? 0.0f : w);
    }
    *reinterpret_cast<f16x8*>(wf + (size_t)gid * 8) = v;
}

// ---------------------------------------------------------------------------
// Kernel B: out[b,t] = sum_n y[n,t]*(z[n,t]+1) - 70,  z = Wm*y  (per b).
// Block = (b, t-tile of 128). 512 threads = 8 waves; wave w owns t w*16..+16.
// Full K=256 reduction per block: W staged in two sequential 64KB halves.
// Y tile (128 t x 256 n) staged transposed [t][m] with XOR swizzle
// (u16 idx ^= (t&7)<<3) for conflict-free ds_read_b128 B-frags.
// No atomics, no memset: each out[b,t] written exactly once.
// ---------------------------------------------------------------------------
__global__ __launch_bounds__(512, 1) void bilinear_kernel(
    const f16* __restrict__ y16, const f16* __restrict__ wf,
    float* __restrict__ out)
{
    __shared__ __align__(16) f16 Wl[32768];   // 64 KB (one W half)
    __shared__ __align__(16) f16 Yl[32768];   // 64 KB (128 t x 256 m)

    const int bi = blockIdx.x;
    const int tt = bi & 7;
    const int b  = bi >> 3;
    const int t0 = tt * 128;
    const int tid = threadIdx.x;

    // stage Y tile: thread (m, t-half) streams a 64-t window of row m,
    // transposes into Yl[t][m^sw]
    {
        const int m    = tid & 255;
        const int half = tid >> 8;
        const f16* ysrc = y16 + ((size_t)(b * ND + m)) * NT + t0 + half * 64;
        #pragma unroll
        for (int c = 0; c < 8; ++c) {
            f16x8 v = *reinterpret_cast<const f16x8*>(ysrc + c * 8);
            #pragma unroll
            for (int e = 0; e < 8; ++e) {
                int tl = half * 64 + c * 8 + e;     // tl&7 == e
                Yl[tl * 256 + (m ^ (e << 3))] = v[e];
            }
        }
    }

    const int lane = tid & 63;
    const int w    = tid >> 6;
    const int tl   = w * 16 + (lane & 15);   // this lane's t column
    const int g    = lane >> 4;
    const int sw   = (tl & 7) << 3;

    float part = 0.f;

    #pragma unroll
    for (int nh = 0; nh < 2; ++nh) {
        // barrier: nh=0 -> Y staging visible before use; nh=1 -> all waves
        // done reading Wl half 0 before overwrite
        __syncthreads();
        const f16* wsrc = wf + (size_t)nh * 32768;
        #pragma unroll
        for (int k = 0; k < 8; ++k) {
            int chunk = k * 512 + tid;
            *reinterpret_cast<f16x8*>(&Wl[chunk * 8]) =
                *reinterpret_cast<const f16x8*>(&wsrc[(size_t)chunk * 8]);
        }
        __syncthreads();

        f32x4 acc[8];
        #pragma unroll
        for (int i = 0; i < 8; ++i) acc[i] = (f32x4){0.f, 0.f, 0.f, 0.f};

        #pragma unroll
        for (int ks = 0; ks < 8; ++ks) {
            const int k0 = ks * 32 + g * 8;
            f16x8 bfrag = *reinterpret_cast<const f16x8*>(&Yl[tl * 256 + (k0 ^ sw)]);
            #pragma unroll
            for (int nt = 0; nt < 8; ++nt) {
                f16x8 afrag = *reinterpret_cast<const f16x8*>(
                    &Wl[((ks * 8 + nt) * 64 + lane) * 8]);
                acc[nt] = __builtin_amdgcn_mfma_f32_16x16x32_f16(
                    afrag, bfrag, acc[nt], 0, 0, 0);
            }
        }

        // epilogue: partial = sum over this half's C rows of y*(z+1)
        #pragma unroll
        for (int nt = 0; nt < 8; ++nt) {
            #pragma unroll
            for (int r = 0; r < 4; ++r) {
                int ng = nh * 128 + nt * 16 + g * 4 + r;   // global n (0..255)
                float yv = (float)Yl[tl * 256 + (ng ^ sw)];
                part = fmaf(yv, acc[nt][r] + 1.0f, part);
            }
        }
    }

    // reduce the 4 lanes sharing the same t (l, l^16, l^32, l^48)
    part += __shfl_xor(part, 16);
    part += __shfl_xor(part, 32);
    if (lane < 16) {
        out[b * NT + t0 + w * 16 + lane] = part - 70.0f;
    }
}

// ---------------------------------------------------------------------------
extern "C" void kernel_launch(void* const* d_in, const int* in_sizes, int n_in,
                              void* d_out, int out_size, void* d_ws, size_t ws_size,
                              hipStream_t stream) {
    const float* x         = (const float*)d_in[0];
    const float* tau_rise  = (const float*)d_in[1];
    const float* tau_decay = (const float*)d_in[2];
    const float* omega     = (const float*)d_in[3];
    const float* W         = (const float*)d_in[4];
    float* out = (float*)d_out;

    f16* y16 = (f16*)d_ws;                                        // 16 MB
    f16* wfr = (f16*)((char*)d_ws + (size_t)16 * 1024 * 1024);    // 128 KB

    wprep_kernel<<<32, 256, 0, stream>>>(W, wfr);
    iir_scan_kernel<<<(NB * ND) / 4, 256, 0, stream>>>(x, tau_rise, tau_decay, omega, y16);
    bilinear_kernel<<<NB * 8, 512, 0, stream>>>(y16, wfr, out);
}

// Round 3
// 24.374 us; speedup vs baseline: 1.6849x; 1.1786x over previous
//
#include <hip/hip_runtime.h>

typedef _Float16 f16;
typedef _Float16 f16x4 __attribute__((ext_vector_type(4)));
typedef _Float16 f16x8 __attribute__((ext_vector_type(8)));
typedef float    f32x4 __attribute__((ext_vector_type(4)));

#define NB 32
#define ND 256
#define NT 1024

// ---------------------------------------------------------------------------
// Fused kernel A: blocks [0,2048) = depthwise causal conv via IIR scan,
// blocks [2048,2080) = W fragment prep.
//
// IIR: one wave per (b,n) row; lane l owns t in [16l,16l+16).
// k[u] = om*(d^u - m^u) => y = om*(S_d - S_m), S_a[t] = x[t] + a*S_a[t-1].
//
// W prep layout: wf[kh(2)][ks(4)][nt(16)][lane(64)][j(8)],
//   value = Wm[n = nt*16+(lane&15)][k = kh*128+ks*32+(lane>>4)*8+j], diag=0.
// ---------------------------------------------------------------------------
__global__ __launch_bounds__(256) void iir_wprep_kernel(
    const float* __restrict__ x, const float* __restrict__ tau_rise,
    const float* __restrict__ tau_decay, const float* __restrict__ omega,
    const float* __restrict__ W, f16* __restrict__ y16, f16* __restrict__ wf)
{
    if (blockIdx.x >= 2048) {
        const int gid  = (blockIdx.x - 2048) * 256 + threadIdx.x;  // 0..8191
        const int kh   = gid >> 12;
        const int ks   = (gid >> 10) & 3;
        const int nt   = (gid >> 6) & 15;
        const int lane = gid & 63;
        const int nrow = nt * 16 + (lane & 15);
        const int k0   = kh * 128 + ks * 32 + (lane >> 4) * 8;
        f16x8 v;
        #pragma unroll
        for (int j = 0; j < 8; ++j) {
            int k = k0 + j;
            float w = W[nrow * 256 + k];
            v[j] = (f16)((k == nrow) ? 0.0f : w);
        }
        *reinterpret_cast<f16x8*>(wf + (size_t)gid * 8) = v;
        return;
    }

    const int lane = threadIdx.x & 63;
    const int wid  = threadIdx.x >> 6;
    const int row  = blockIdx.x * 4 + wid;      // b*ND + n
    const int n    = row & (ND - 1);

    const float td = tau_decay[n];
    const float tr = tau_rise[n];
    const float om = omega[n];
    const float ad = expf(-1.0f / td);
    const float am = expf(-(1.0f / tr + 1.0f / td));

    const float* xr = x + (size_t)row * NT + lane * 16;
    float xv[16];
    #pragma unroll
    for (int i = 0; i < 4; ++i) {
        f32x4 v = *reinterpret_cast<const f32x4*>(xr + i * 4);
        xv[i*4+0] = v[0]; xv[i*4+1] = v[1]; xv[i*4+2] = v[2]; xv[i*4+3] = v[3];
    }

    // local (carry-free) inclusive scans, both states
    float ld[16], lm[16];
    float sd = 0.f, sm = 0.f;
    #pragma unroll
    for (int i = 0; i < 16; ++i) {
        sd = fmaf(ad, sd, xv[i]); ld[i] = sd;
        sm = fmaf(am, sm, xv[i]); lm[i] = sm;
    }

    // a^16 for each state
    float t2;
    t2 = ad * ad; t2 = t2 * t2; t2 = t2 * t2; const float a16d = t2 * t2;
    t2 = am * am; t2 = t2 * t2; t2 = t2 * t2; const float a16m = t2 * t2;

    // weighted Kogge-Stone across lanes: X_l = sum_j a16^(l-j) H_j
    float Xd = sd, Xm = sm;
    float wdp = a16d, wmp = a16m;
    #pragma unroll
    for (int off = 1; off < 64; off <<= 1) {
        float pd = __shfl_up(Xd, off);
        float pm = __shfl_up(Xm, off);
        if (lane >= off) { Xd = fmaf(wdp, pd, Xd); Xm = fmaf(wmp, pm, Xm); }
        wdp *= wdp; wmp *= wmp;
    }
    // exclusive carry = running state at end of previous lane's chunk
    float cd = __shfl_up(Xd, 1);
    float cm = __shfl_up(Xm, 1);
    if (lane == 0) { cd = 0.f; cm = 0.f; }

    // reconstruct: S[16l+i] = local_i + a^(i+1) * carry
    f16x8 o0, o1;
    float pd = ad, pm = am;
    #pragma unroll
    for (int i = 0; i < 16; ++i) {
        float yd = fmaf(pd, cd, ld[i]);
        float ym = fmaf(pm, cm, lm[i]);
        float yv = om * (yd - ym);
        if (i < 8) o0[i] = (f16)yv; else o1[i - 8] = (f16)yv;
        pd *= ad; pm *= am;
    }
    f16* dst = y16 + (size_t)row * NT + lane * 16;
    *reinterpret_cast<f16x8*>(dst)     = o0;
    *reinterpret_cast<f16x8*>(dst + 8) = o1;
}

// ---------------------------------------------------------------------------
// Kernel B: out[b,t] = sum_n y[n,t]*(z[n,t]+1) - 70,  z = Wm*y  (per b).
// Block = (b, t-tile of 128), 512 threads = 8 waves arranged 2(t) x 4(n):
// wave owns 64t x 64n, full K=256 via two sequentially-staged 64KB W K-halves
// (acc persists across halves). Per ks: 4 A-reads + 4 B-reads -> 16 MFMAs.
// Y tile staged transposed [t][m] with XOR swizzle (u16 idx ^= (t&7)<<3).
// Cross-wave (wn) reduction via sbuf; each out written once, no atomics.
// ---------------------------------------------------------------------------
__global__ __launch_bounds__(512, 1) void bilinear_kernel(
    const f16* __restrict__ y16, const f16* __restrict__ wf,
    float* __restrict__ out)
{
    __shared__ __align__(16) f16 Wl[32768];    // 64 KB (one K-half of W)
    __shared__ __align__(16) f16 Yl[32768];    // 64 KB (128 t x 256 n)
    __shared__ float sbuf[4][128];             // 2 KB cross-wave partials

    const int bi = blockIdx.x;
    const int tt = bi & 7;
    const int b  = bi >> 3;
    const int t0 = tt * 128;
    const int tid = threadIdx.x;

    // --- issue Y global loads (thread = (m, t-half), 64-t window of row m)
    const int m    = tid & 255;
    const int half = tid >> 8;
    const f16* ysrc = y16 + ((size_t)(b * ND + m)) * NT + t0 + half * 64;
    f16x8 vy[8];
    #pragma unroll
    for (int c = 0; c < 8; ++c)
        vy[c] = *reinterpret_cast<const f16x8*>(ysrc + c * 8);

    // --- issue W kh=0 loads (64KB / 512 threads = 8 x f16x8 per thread)
    f16x8 vw[8];
    #pragma unroll
    for (int k = 0; k < 8; ++k)
        vw[k] = *reinterpret_cast<const f16x8*>(&wf[(size_t)(k * 512 + tid) * 8]);

    // --- transpose-write Y into LDS
    #pragma unroll
    for (int c = 0; c < 8; ++c) {
        #pragma unroll
        for (int e = 0; e < 8; ++e) {
            int tl = half * 64 + c * 8 + e;     // tl&7 == e
            Yl[tl * 256 + (m ^ (e << 3))] = vy[c][e];
        }
    }
    // --- write W kh=0 into LDS, then issue kh=1 loads
    #pragma unroll
    for (int k = 0; k < 8; ++k)
        *reinterpret_cast<f16x8*>(&Wl[(k * 512 + tid) * 8]) = vw[k];
    #pragma unroll
    for (int k = 0; k < 8; ++k)
        vw[k] = *reinterpret_cast<const f16x8*>(
            &wf[(size_t)(32768 / 8 + k * 512 + tid) * 8]);

    const int lane = tid & 63;
    const int w    = tid >> 6;
    const int wt   = w >> 2;          // 0..1: t 64-range
    const int wn   = w & 3;           // 0..3: n 64-range
    const int g    = lane >> 4;

    int tl4[4], sw4[4];
    #pragma unroll
    for (int tf = 0; tf < 4; ++tf) {
        tl4[tf] = wt * 64 + tf * 16 + (lane & 15);
        sw4[tf] = (tl4[tf] & 7) << 3;
    }

    f32x4 acc[4][4];                  // [a: nt sub][tf]
    #pragma unroll
    for (int a = 0; a < 4; ++a)
        #pragma unroll
        for (int tf = 0; tf < 4; ++tf) acc[a][tf] = (f32x4){0.f,0.f,0.f,0.f};

    #pragma unroll
    for (int kh = 0; kh < 2; ++kh) {
        __syncthreads();              // kh0: staging visible; kh1: Wl reads done
        if (kh == 1) {
            #pragma unroll
            for (int k = 0; k < 8; ++k)
                *reinterpret_cast<f16x8*>(&Wl[(k * 512 + tid) * 8]) = vw[k];
            __syncthreads();
        }
        #pragma unroll
        for (int ks = 0; ks < 4; ++ks) {
            f16x8 bfrag[4];
            #pragma unroll
            for (int tf = 0; tf < 4; ++tf) {
                int m0 = kh * 128 + ks * 32 + g * 8;
                bfrag[tf] = *reinterpret_cast<const f16x8*>(
                    &Yl[tl4[tf] * 256 + (m0 ^ sw4[tf])]);
            }
            #pragma unroll
            for (int a = 0; a < 4; ++a) {
                int nt = wn * 4 + a;
                f16x8 afrag = *reinterpret_cast<const f16x8*>(
                    &Wl[((ks * 16 + nt) * 64 + lane) * 8]);
                #pragma unroll
                for (int tf = 0; tf < 4; ++tf)
                    acc[a][tf] = __builtin_amdgcn_mfma_f32_16x16x32_f16(
                        afrag, bfrag[tf], acc[a][tf], 0, 0, 0);
            }
        }
    }

    // epilogue: per t-col partial = sum over this wave's 64 n of y*(z+1)
    #pragma unroll
    for (int tf = 0; tf < 4; ++tf) {
        float p = 0.f;
        #pragma unroll
        for (int a = 0; a < 4; ++a) {
            int n0 = (wn * 4 + a) * 16 + g * 4;
            f16x4 yv4 = *reinterpret_cast<const f16x4*>(
                &Yl[tl4[tf] * 256 + (n0 ^ sw4[tf])]);
            #pragma unroll
            for (int r = 0; r < 4; ++r)
                p = fmaf((float)yv4[r], acc[a][tf][r] + 1.0f, p);
        }
        p += __shfl_xor(p, 16);
        p += __shfl_xor(p, 32);
        if (lane < 16) sbuf[wn][wt * 64 + tf * 16 + lane] = p;
    }
    __syncthreads();
    if (tid < 128) {
        out[b * NT + t0 + tid] =
            sbuf[0][tid] + sbuf[1][tid] + sbuf[2][tid] + sbuf[3][tid] - 70.0f;
    }
}

// ---------------------------------------------------------------------------
extern "C" void kernel_launch(void* const* d_in, const int* in_sizes, int n_in,
                              void* d_out, int out_size, void* d_ws, size_t ws_size,
                              hipStream_t stream) {
    const float* x         = (const float*)d_in[0];
    const float* tau_rise  = (const float*)d_in[1];
    const float* tau_decay = (const float*)d_in[2];
    const float* omega     = (const float*)d_in[3];
    const float* W         = (const float*)d_in[4];
    float* out = (float*)d_out;

    f16* y16 = (f16*)d_ws;                                        // 16 MB
    f16* wfr = (f16*)((char*)d_ws + (size_t)16 * 1024 * 1024);    // 128 KB

    iir_wprep_kernel<<<2048 + 32, 256, 0, stream>>>(
        x, tau_rise, tau_decay, omega, W, y16, wfr);
    bilinear_kernel<<<NB * 8, 512, 0, stream>>>(y16, wfr, out);
}